// Round 3
// baseline (425.255 us; speedup 1.0000x reference)
//
#include <hip/hip_runtime.h>
#include <stdint.h>

// CostVolume: out[b, d=(dy+4)*9+(dx+4), h, w] =
//   leaky_relu( mean_c( x1[b,c,h,w] * x2[b,c,h+dy,w+dx] ), 0.1 ), zero-padded x2.
//
// Round 3: latency-bound fix. dy split across 3 block groups (acc 72->24 regs,
// occupancy 43%->~75%), float4 staging loads (4x fewer VMEM instr), KC=64
// (half the barriers), x1 staged through LDS too. bf16 MFMA 16x16x32 along w,
// band extraction + LDS transpose epilogue as before.

#define CCH   128
#define HH    96
#define WW    320
#define HWs   (HH * WW)      // 30720
#define CHWs  (CCH * HWs)
#define ND    81

#define TH 4    // output h rows per block
#define WT 32   // output w cols per block (2 M-tiles of 16)
#define SW 40   // staged x2 cols: W0-4 .. W0+35
#define SRr 6   // staged x2 rows: dy-group window (4 rows + 2 halo)
#define KC 64   // channels per chunk (two MFMA K-steps)
#define KP 68   // padded k-stride in shorts: 136B -> 2-way banks on frag reads (free)
#define OP 132  // obuf d-slice stride in floats

#define X2_LDS (SRr * SW * KP * 2)              // 32640 B
#define X1_LDS (TH * WT * KP * 2)               // 17408 B
// total 50048 B -> 3 blocks/CU by LDS

typedef __attribute__((ext_vector_type(8))) short        short8;
typedef __attribute__((ext_vector_type(4))) float        floatx4;

// round-to-nearest-even fp32 -> bf16 pack (inputs are normals; no NaN path)
__device__ __forceinline__ unsigned int bf16rne(float f) {
  unsigned int u = __float_as_uint(f);
  return (u + 0x7fffu + ((u >> 16) & 1u)) >> 16;
}
__device__ __forceinline__ unsigned int pk2(float lo, float hi) {
  return bf16rne(lo) | (bf16rne(hi) << 16);
}

__global__ __launch_bounds__(512, 6) void cost_volume_kernel(
    const float* __restrict__ x1g, const float* __restrict__ x2g,
    float* __restrict__ out)
{
  extern __shared__ char smem[];
  short* x2s  = (short*)smem;                 // [r 0..5][w 0..39][k 0..63] pad KP
  short* x1s  = (short*)(smem + X2_LDS);      // [h*32+w][k] pad KP
  float* obuf = (float*)smem;                 // epilogue alias: 27*OP floats

  // grid: b fastest (XCD spread), then dy-group (same-tile groups -> same XCD)
  const int b    = blockIdx.x & 7;
  const int y    = blockIdx.x >> 3;
  const int g3   = y % 3;                     // dy group: dy = g3*3 + dyl
  const int tile = y / 3;
  const int hs   = tile % 24;
  const int ws   = tile / 24;
  const int h0   = hs * TH;
  const int W0   = ws * WT;

  const int t    = threadIdx.x;
  const int wave = t >> 6;
  const int lane = t & 63;
  const int hl   = wave >> 1;   // 0..3: h row owned by this wave
  const int mt   = wave & 1;    // 0..1: M-tile owned by this wave
  const int q    = lane >> 4;   // quad
  const int ln   = lane & 15;

  const float* x1b = x1g + (size_t)b * CHWs;
  const float* x2b = x2g + (size_t)b * CHWs;

  // ---- x2 staging decode: unit = (row r, channel-pair cp, w-quad wq) ----
  // 6*32*10 = 1920 units; each: 2 aligned float4 loads -> 4 packed u32 -> LDS
  int x2_go[4], x2_lo[4];
#pragma unroll
  for (int s = 0; s < 4; ++s) {
    int u = t + s * 512;
    if (u < SRr * 32 * 10) {
      int wq  = u % 10;
      int tmp = u / 10;
      int cp  = tmp % 32;
      int r   = tmp / 32;
      int gr  = h0 + g3 * 3 - 4 + r;
      int gc0 = W0 - 4 + wq * 4;
      x2_lo[s] = (r * SW + wq * 4) * KP + cp * 2;
      x2_go[s] = (gr >= 0 && gr < HH && gc0 >= 0 && gc0 <= WW - 4)
                   ? (cp * 2 * HWs + gr * WW + gc0) : -1;
    } else { x2_lo[s] = -1; x2_go[s] = -1; }
  }
  // ---- x1 staging decode: 4*32*8 = 1024 units, exactly 2 per thread ----
  int x1_go[2], x1_lo[2];
#pragma unroll
  for (int s = 0; s < 2; ++s) {
    int u   = t + s * 512;
    int wq  = u % 8;
    int tmp = u / 8;
    int cp  = tmp % 32;
    int hr  = tmp / 32;
    x1_lo[s] = (hr * WT + wq * 4) * KP + cp * 2;
    x1_go[s] = cp * 2 * HWs + (h0 + hr) * WW + W0 + wq * 4;
  }

  floatx4 acc[3][2] = {};   // 24 VGPRs

  for (int kc = 0; kc < CCH / KC; ++kc) {
    const int cbase = kc * KC * HWs;

    // ---- stage x2: two float4 (channels c, c+1) -> 4 bf16x2 at [w+i][c] ----
#pragma unroll
    for (int s = 0; s < 4; ++s) {
      if (x2_lo[s] >= 0) {
        if (x2_go[s] >= 0) {
          const float4 fa = *(const float4*)(x2b + cbase + x2_go[s]);
          const float4 fb = *(const float4*)(x2b + cbase + x2_go[s] + HWs);
          *(unsigned int*)&x2s[x2_lo[s] + 0 * KP] = pk2(fa.x, fb.x);
          *(unsigned int*)&x2s[x2_lo[s] + 1 * KP] = pk2(fa.y, fb.y);
          *(unsigned int*)&x2s[x2_lo[s] + 2 * KP] = pk2(fa.z, fb.z);
          *(unsigned int*)&x2s[x2_lo[s] + 3 * KP] = pk2(fa.w, fb.w);
        } else {
          *(unsigned int*)&x2s[x2_lo[s] + 0 * KP] = 0u;
          *(unsigned int*)&x2s[x2_lo[s] + 1 * KP] = 0u;
          *(unsigned int*)&x2s[x2_lo[s] + 2 * KP] = 0u;
          *(unsigned int*)&x2s[x2_lo[s] + 3 * KP] = 0u;
        }
      }
    }
    // ---- stage x1 ----
#pragma unroll
    for (int s = 0; s < 2; ++s) {
      const float4 fa = *(const float4*)(x1b + cbase + x1_go[s]);
      const float4 fb = *(const float4*)(x1b + cbase + x1_go[s] + HWs);
      *(unsigned int*)&x1s[x1_lo[s] + 0 * KP] = pk2(fa.x, fb.x);
      *(unsigned int*)&x1s[x1_lo[s] + 1 * KP] = pk2(fa.y, fb.y);
      *(unsigned int*)&x1s[x1_lo[s] + 2 * KP] = pk2(fa.z, fb.z);
      *(unsigned int*)&x1s[x1_lo[s] + 3 * KP] = pk2(fa.w, fb.w);
    }
    __syncthreads();

    // ---- MFMA: 2 K-steps x 3 dyl x 2 jn per wave ----
#pragma unroll
    for (int ks = 0; ks < 2; ++ks) {
      const short8 af = *(const short8*)
          &x1s[(hl * WT + mt * 16 + ln) * KP + ks * 32 + q * 8];
#pragma unroll
      for (int dyl = 0; dyl < 3; ++dyl) {
        const int r = hl + dyl;
#pragma unroll
        for (int jn = 0; jn < 2; ++jn) {
          int jc = (mt + jn) * 16 + ln;
          if (jc > SW - 1) jc = SW - 1;   // clamped lanes are never extracted
          const short8 bf = *(const short8*)
              &x2s[(r * SW + jc) * KP + ks * 32 + q * 8];
          acc[dyl][jn] = __builtin_amdgcn_mfma_f32_16x16x32_bf16(
              af, bf, acc[dyl][jn], 0, 0, 0);
        }
      }
    }
    __syncthreads();
  }

  // ---- epilogue: band extraction dx+4 = jn*16 + n - m, 27 d-slices ----
#pragma unroll
  for (int dyl = 0; dyl < 3; ++dyl)
#pragma unroll
    for (int jn = 0; jn < 2; ++jn)
#pragma unroll
      for (int reg = 0; reg < 4; ++reg) {
        const int m   = q * 4 + reg;
        const int dxi = jn * 16 + ln - m;
        if (dxi >= 0 && dxi < 9) {
          float v = acc[dyl][jn][reg] * (1.0f / 128.0f);
          v = (v < 0.0f) ? 0.1f * v : v;
          obuf[(dyl * 9 + dxi) * OP + hl * WT + mt * 16 + m] = v;
        }
      }
  __syncthreads();

  // ---- coalesced write-out: 27 slices x TH x WT = 3456 floats ----
  const size_t obase = (size_t)b * (ND * (size_t)HWs)
                     + (size_t)(g3 * 27) * HWs;
  for (int idx = t; idx < 27 * TH * WT; idx += 512) {
    const int dl  = idx >> 7;     // /(TH*WT)=128
    const int rem = idx & 127;
    const int hh  = rem >> 5;
    const int wl  = rem & 31;
    out[obase + (size_t)dl * HWs + (h0 + hh) * WW + W0 + wl]
        = obuf[dl * OP + rem];
  }
}

extern "C" void kernel_launch(void* const* d_in, const int* in_sizes, int n_in,
                              void* d_out, int out_size, void* d_ws, size_t ws_size,
                              hipStream_t stream) {
  const float* x1 = (const float*)d_in[0];
  const float* x2 = (const float*)d_in[1];
  float* out = (float*)d_out;
  // grid: 24 hs x 10 ws tiles x 3 dy-groups x 8 batches = 5760 blocks
  cost_volume_kernel<<<dim3(5760), dim3(512), X2_LDS + X1_LDS, stream>>>(x1, x2, out);
}